// Round 23
// baseline (169.730 us; speedup 1.0000x reference)
//
#include <hip/hip_runtime.h>
#include <math.h>

#define N_NODES 50000
#define E_EDGES 800000
#define IN_DIM  256
#define D_DIM   96
#define OUT_DIM 128
#define BKT     64         // fixed bucket stride (deg ~ Poisson(16); P(>=64) ~ 1e-18)
#define PREP_BLOCKS 448
#define FEAT_BLOCKS 782    // (50000+63)/64
#define BUCK_BLOCKS 3125   // ceil(E/256)
#define NTILES      3125   // 16-node tiles (3125*16 = 50000 exactly)

typedef __attribute__((ext_vector_type(8))) short short8;
typedef __attribute__((ext_vector_type(4))) float f32x4;

__device__ __forceinline__ unsigned short f2bf(float f) {
    unsigned u = __float_as_uint(f);
    unsigned r = u + 0x7fffu + ((u >> 16) & 1u);
    return (unsigned short)(r >> 16);
}
__device__ __forceinline__ float bf2f(unsigned short u) {
    return __uint_as_float(((unsigned)u) << 16);
}
__device__ __forceinline__ float sigm(float x) { return 1.f / (1.f + __expf(-x)); }
__device__ __forceinline__ float ftanh(float x) { return 1.f - 2.f / (1.f + __expf(2.f * x)); }

// slot swizzle: 16B slot s -> s ^ ((s>>4)&7). Same involution on write & read.
__device__ __forceinline__ int swz(int s) { return s ^ ((s >> 4) & 7); }

// pack 8 consecutive f32 -> short8 of bf16
__device__ __forceinline__ short8 pack8(const float* __restrict__ p) {
    float4 v0 = *(const float4*)p;
    float4 v1 = *(const float4*)(p + 4);
    union { short8 s; unsigned u[4]; } r;
    r.u[0] = (unsigned)f2bf(v0.x) | ((unsigned)f2bf(v0.y) << 16);
    r.u[1] = (unsigned)f2bf(v0.z) | ((unsigned)f2bf(v0.w) << 16);
    r.u[2] = (unsigned)f2bf(v1.x) | ((unsigned)f2bf(v1.y) << 16);
    r.u[3] = (unsigned)f2bf(v1.z) | ((unsigned)f2bf(v1.w) << 16);
    return r.s;
}

// ---------- K0: weight prep only ----------
__global__ __launch_bounds__(256)
void k_prep(const float* __restrict__ Wfc, const float* __restrict__ W_ih,
            const float* __restrict__ W_hh, const float* __restrict__ b_ih,
            const float* __restrict__ b_hh,
            unsigned short* __restrict__ Wfc_frag,
            unsigned short* __restrict__ Wb_frag, float* __restrict__ bsum) {
    int tid = blockIdx.x * 256 + threadIdx.x;
    if (tid < 512) bsum[tid] = b_ih[tid] + b_hh[tid];
    if (tid < 6 * 8 * 64 * 8) {          // Wfc_frag
        int j = tid & 7;
        int rest = tid >> 3;
        int l = rest & 63;
        int rest2 = rest >> 6;
        int ks = rest2 & 7;
        int cf = rest2 >> 3;
        int k   = ks * 32 + (l >> 4) * 8 + j;
        int col = cf * 16 + (l & 15);
        Wfc_frag[tid] = f2bf(Wfc[k * D_DIM + col]);
    }
    if (tid < 32 * 7 * 64 * 8) {         // Wb_frag
        int j = tid & 7;
        int rest = tid >> 3;
        int l = rest & 63;
        int rest2 = rest >> 6;
        int ks = rest2 % 7;
        int cf = rest2 / 7;
        int k   = ks * 32 + (l >> 4) * 8 + j;
        int col = cf * 16 + (l & 15);
        float v = (k < 96) ? W_ih[col * 96 + k] : W_hh[col * 128 + (k - 96)];
        Wb_frag[tid] = f2bf(v);
    }
}

// ---------- merged: featmm (blocks 0..781) | edge bucket (rest) ----------
__global__ __launch_bounds__(256, 2)
void k_featmm_bucket(const float* __restrict__ x,
                     const unsigned short* __restrict__ Wfc_frag,
                     const float* __restrict__ al, const float* __restrict__ ar,
                     unsigned short* __restrict__ feat,
                     float* __restrict__ el, float* __restrict__ er,
                     const int* __restrict__ src, const int* __restrict__ dst,
                     int* __restrict__ cnt, unsigned short* __restrict__ ebuf16) {
    if (blockIdx.x >= FEAT_BLOCKS) {
        int e = (blockIdx.x - FEAT_BLOCKS) * 256 + threadIdx.x;
        if (e < E_EDGES) {
            int d = dst[e];
            int pos = atomicAdd(&cnt[d], 1);
            __builtin_nontemporal_store((unsigned short)src[e],
                                        ebuf16 + (size_t)d * BKT + pos);
        }
        return;
    }
    const int t     = threadIdx.x;
    const int lane  = t & 63;
    const int w     = t >> 6;
    const int nfrag = lane & 15;
    const int khalf = lane >> 4;
    const int node  = blockIdx.x * 64 + w * 16 + nfrag;
    const int r     = min(node, N_NODES - 1);

    f32x4 acc[6];
#pragma unroll
    for (int cf = 0; cf < 6; ++cf) acc[cf] = (f32x4){0.f, 0.f, 0.f, 0.f};

    const float* px = x + (size_t)r * IN_DIM + khalf * 8;
    const unsigned short* pW = Wfc_frag + (size_t)lane * 8;

#pragma unroll 1
    for (int ks = 0; ks < 8; ++ks) {
        short8 xf = pack8(px + ks * 32);
#pragma unroll
        for (int cf = 0; cf < 6; ++cf) {
            short8 wf = *(const short8*)(pW + (size_t)((cf * 8 + ks) * 64) * 8);
            acc[cf] = __builtin_amdgcn_mfma_f32_16x16x32_bf16(wf, xf, acc[cf], 0, 0, 0);
        }
    }

    float sl = 0.f, sr = 0.f;
#pragma unroll
    for (int cf = 0; cf < 6; ++cf) {
        const int oc = cf * 16 + khalf * 4;
        const float4 a = *(const float4*)(al + oc);
        const float4 b = *(const float4*)(ar + oc);
        sl += acc[cf][0]*a.x + acc[cf][1]*a.y + acc[cf][2]*a.z + acc[cf][3]*a.w;
        sr += acc[cf][0]*b.x + acc[cf][1]*b.y + acc[cf][2]*b.z + acc[cf][3]*b.w;
    }
    sl += __shfl_xor(sl, 16, 64); sl += __shfl_xor(sl, 32, 64);
    sr += __shfl_xor(sr, 16, 64); sr += __shfl_xor(sr, 32, 64);

    if (node < N_NODES) {
        if (lane < 16) { el[node] = sl; er[node] = sr; }
#pragma unroll
        for (int cf = 0; cf < 6; ++cf) {
            const int oc = cf * 16 + khalf * 4;
            union { unsigned u[2]; } pk;
            pk.u[0] = (unsigned)f2bf(acc[cf][0]) | ((unsigned)f2bf(acc[cf][1]) << 16);
            pk.u[1] = (unsigned)f2bf(acc[cf][2]) | ((unsigned)f2bf(acc[cf][3]) << 16);
            *(uint2*)(feat + (size_t)node * D_DIM + oc) = make_uint2(pk.u[0], pk.u[1]);
        }
    }
}

// ---------- K3d: softmax-gather -> xmid bf16 [N,96] (R17 form) ----------
__global__ __launch_bounds__(256)
void k_gather(const int* __restrict__ cnt, const unsigned short* __restrict__ ebuf16,
              const float* __restrict__ el, const float* __restrict__ er,
              const unsigned short* __restrict__ feat, const float* __restrict__ bias,
              unsigned short* __restrict__ xmid) {
    const int n    = (blockIdx.x * 256 + threadIdx.x) >> 5;
    const int lane = threadIdx.x & 31;
    if (n >= N_NODES) return;
    const size_t o0 = (size_t)n * BKT;
    const int deg = cnt[n];
    const float ern = er[n];

    float a0 = 0.f, a1 = 0.f, a2 = 0.f;
    float inv;

    if (deg <= 32) {
        int   s_l = 0;
        float v_l = -INFINITY;
        if (lane < deg) {
            s_l = ebuf16[o0 + lane];
            float v = el[s_l] + ern; v_l = v > 0.f ? v : 0.2f * v;
        }
        float vmax = v_l;
#pragma unroll
        for (int d = 16; d; d >>= 1) vmax = fmaxf(vmax, __shfl_xor(vmax, d, 32));
        float w_l = (lane < deg) ? __expf(v_l - vmax) : 0.f;
        float ssum = w_l;
#pragma unroll
        for (int d = 16; d; d >>= 1) ssum += __shfl_xor(ssum, d, 32);
        inv = 1.f / (ssum > 0.f ? ssum : 1.f);

        for (int i = 0; i < deg; ++i) {
            int   s = __shfl(s_l, i, 32);
            float w = __shfl(w_l, i, 32);
            const unsigned short* fr = feat + (size_t)s * D_DIM;
            a0 += w * bf2f(fr[lane]);
            a1 += w * bf2f(fr[lane + 32]);
            a2 += w * bf2f(fr[lane + 64]);
        }
    } else {
        float vmax = -INFINITY;
        for (int i = lane; i < deg; i += 32) {
            int s = ebuf16[o0 + i];
            float v = el[s] + ern; v = v > 0.f ? v : 0.2f * v;
            vmax = fmaxf(vmax, v);
        }
#pragma unroll
        for (int d = 16; d; d >>= 1) vmax = fmaxf(vmax, __shfl_xor(vmax, d, 32));

        float ssum = 0.f;
        for (int i = lane; i < deg; i += 32) {
            int s = ebuf16[o0 + i];
            float v = el[s] + ern; v = v > 0.f ? v : 0.2f * v;
            ssum += __expf(v - vmax);
        }
#pragma unroll
        for (int d = 16; d; d >>= 1) ssum += __shfl_xor(ssum, d, 32);
        inv = 1.f / (ssum > 0.f ? ssum : 1.f);

        for (int bi0 = 0; bi0 < deg; bi0 += 32) {
            int   i_l = bi0 + lane;
            int   s_l = 0; float w_l = 0.f;
            if (i_l < deg) {
                s_l = ebuf16[o0 + i_l];
                float v = el[s_l] + ern; v = v > 0.f ? v : 0.2f * v;
                w_l = __expf(v - vmax);
            }
            int m = min(32, deg - bi0);
            for (int i = 0; i < m; ++i) {
                int   s = __shfl(s_l, i, 32);
                float w = __shfl(w_l, i, 32);
                const unsigned short* fr = feat + (size_t)s * D_DIM;
                a0 += w * bf2f(fr[lane]);
                a1 += w * bf2f(fr[lane + 32]);
                a2 += w * bf2f(fr[lane + 64]);
            }
        }
    }

    unsigned short* zr = xmid + (size_t)n * D_DIM;
    zr[lane]      = f2bf(ftanh(a0 * inv + bias[lane]));
    zr[lane + 32] = f2bf(ftanh(a1 * inv + bias[lane + 32]));
    zr[lane + 64] = f2bf(ftanh(a2 * inv + bias[lane + 64]));
}

// ---------- K4: persistent-block LSTM GEMM, weights in LDS, h0 cast fused ----------
// 256 blocks (1/CU). Block handles col-half ch = blockIdx>>7 (64 of 128 cols),
// loads its 114.7KB weight slice to LDS ONCE, then grid-strides ~24 node
// tiles (16 nodes each) with double-buffered reg->LDS A staging. h0 is read
// as f32 and cast to bf16 in-register during the stage (no separate pass).
__global__ __launch_bounds__(256, 1)
void k_lstm_persist(const unsigned short* __restrict__ xmid,   // [N,96]  bf16
                    const float* __restrict__ h0,              // [N,128] f32
                    const unsigned short* __restrict__ Wb_frag,
                    const float* __restrict__ bsum,
                    const float* __restrict__ cin0,
                    float* __restrict__ out_h1a, float* __restrict__ out_h1b,
                    float* __restrict__ out_c1) {
    __shared__ unsigned short wlds[16 * 7 * 64 * 8];   // 114,688 B
    __shared__ unsigned short alds[2][7 * 64 * 8];     //  14,336 B
    const int t     = threadIdx.x;
    const int lane  = t & 63;
    const int wv    = t >> 6;
    const int nfrag = lane & 15;
    const int khalf = lane >> 4;
    const int ch    = blockIdx.x >> 7;       // col-half 0/1
    const int b7    = blockIdx.x & 127;      // tile lane

    // ---- load weight slice: 7168 x 16B chunks, coalesced ----
#pragma unroll 4
    for (int it = 0; it < 28; ++it) {
        int cidx = t + it * 256;             // < 7168 always
        int wg   = cidx / 448;               // wv*4+g
        int rem  = cidx % 448;               // ks*64+l
        int cf   = ch * 4 + (wg >> 2) + 8 * (wg & 3);
        *(short8*)(wlds + (size_t)cidx * 8) =
            *(const short8*)(Wb_frag + ((size_t)cf * 448 + rem) * 8);
    }

    // per-thread constant bias (col set fixed for whole block)
    const int oc = ch * 64 + wv * 16 + khalf * 4;
    const float4 bi = *(const float4*)(bsum + oc);
    const float4 bf = *(const float4*)(bsum + 128 + oc);
    const float4 bg = *(const float4*)(bsum + 256 + oc);
    const float4 bo = *(const float4*)(bsum + 384 + oc);

    const int U = (NTILES - b7 + 127) / 128;

    // prefetch chunks: q0 = t (<256), q1 = t+256 (valid if t<192); 448 total
    short8 r0, r1;
    int s0 = 0, s1 = 0;
    {
        int tile = b7, n0 = tile * 16;
        { int q = t;
          if (q < 192) { int rr = q / 12, ck = q % 12;
              r0 = *(const short8*)(xmid + (size_t)(n0 + rr) * D_DIM + ck * 8);
              s0 = (ck >> 2) * 64 + (ck & 3) * 16 + rr;
          } else { int p = q - 192; int rr = p >> 4, ck = p & 15;
              r0 = pack8(h0 + (size_t)(n0 + rr) * OUT_DIM + ck * 8);
              s0 = (3 + (ck >> 2)) * 64 + (ck & 3) * 16 + rr; } }
        if (t < 192) { int p = t + 64;       // q1 = t+256 -> h0 part, p = q1-192
            int rr = p >> 4, ck = p & 15;
            r1 = pack8(h0 + (size_t)(n0 + rr) * OUT_DIM + ck * 8);
            s1 = (3 + (ck >> 2)) * 64 + (ck & 3) * 16 + rr; }
    }
    // write tile 0 into alds[0]
    *(short8*)(alds[0] + (size_t)swz(s0) * 8) = r0;
    if (t < 192) *(short8*)(alds[0] + (size_t)swz(s1) * 8) = r1;
    __syncthreads();

    for (int u = 0; u < U; ++u) {
        const int cur  = u & 1;
        const int tile = b7 + u * 128;
        const int n0   = tile * 16;
        const int node = n0 + nfrag;

        // issue next tile's prefetch (hides under compute)
        if (u + 1 < U) {
            int nn0 = (tile + 128) * 16;
            { int q = t;
              if (q < 192) { int rr = q / 12, ck = q % 12;
                  r0 = *(const short8*)(xmid + (size_t)(nn0 + rr) * D_DIM + ck * 8);
              } else { int p = q - 192; int rr = p >> 4, ck = p & 15;
                  r0 = pack8(h0 + (size_t)(nn0 + rr) * OUT_DIM + ck * 8); } }
            if (t < 192) { int p = t + 64;
                int rr = p >> 4, ck = p & 15;
                r1 = pack8(h0 + (size_t)(nn0 + rr) * OUT_DIM + ck * 8); }
        }

        const float4 cv = *(const float4*)(cin0 + (size_t)node * OUT_DIM + oc);

        f32x4 acc[4];
#pragma unroll
        for (int g = 0; g < 4; ++g) acc[g] = (f32x4){0.f, 0.f, 0.f, 0.f};

#pragma unroll
        for (int ks = 0; ks < 7; ++ks) {
            short8 zf = *(const short8*)(alds[cur] + (size_t)swz(ks * 64 + lane) * 8);
#pragma unroll
            for (int g = 0; g < 4; ++g) {
                short8 wf = *(const short8*)(wlds +
                    (size_t)(((wv * 4 + g) * 7 + ks) * 64 + lane) * 8);
                acc[g] = __builtin_amdgcn_mfma_f32_16x16x32_bf16(wf, zf, acc[g], 0, 0, 0);
            }
        }

        // epilogue: 4 cols per lane, all 4 gates in-register
        {
            float4 h1, c1;
            c1.x = sigm(acc[1][0] + bf.x) * cv.x + sigm(acc[0][0] + bi.x) * ftanh(acc[2][0] + bg.x);
            c1.y = sigm(acc[1][1] + bf.y) * cv.y + sigm(acc[0][1] + bi.y) * ftanh(acc[2][1] + bg.y);
            c1.z = sigm(acc[1][2] + bf.z) * cv.z + sigm(acc[0][2] + bi.z) * ftanh(acc[2][2] + bg.z);
            c1.w = sigm(acc[1][3] + bf.w) * cv.w + sigm(acc[0][3] + bi.w) * ftanh(acc[2][3] + bg.w);
            h1.x = sigm(acc[3][0] + bo.x) * ftanh(c1.x);
            h1.y = sigm(acc[3][1] + bo.y) * ftanh(c1.y);
            h1.z = sigm(acc[3][2] + bo.z) * ftanh(c1.z);
            h1.w = sigm(acc[3][3] + bo.w) * ftanh(c1.w);
            *(float4*)(out_h1a + (size_t)node * OUT_DIM + oc) = h1;
            *(float4*)(out_h1b + (size_t)node * OUT_DIM + oc) = h1;
            *(float4*)(out_c1  + (size_t)node * OUT_DIM + oc) = c1;
        }

        // stage next tile into the other buffer
        if (u + 1 < U) {
            *(short8*)(alds[cur ^ 1] + (size_t)swz(s0) * 8) = r0;
            if (t < 192) *(short8*)(alds[cur ^ 1] + (size_t)swz(s1) * 8) = r1;
        }
        __syncthreads();
    }
}

extern "C" void kernel_launch(void* const* d_in, const int* in_sizes, int n_in,
                              void* d_out, int out_size, void* d_ws, size_t ws_size,
                              hipStream_t stream) {
    const float* x      = (const float*)d_in[0];
    const float* W_fc   = (const float*)d_in[1];
    const float* attn_l = (const float*)d_in[2];
    const float* attn_r = (const float*)d_in[3];
    const float* bias   = (const float*)d_in[4];
    const float* W_ih   = (const float*)d_in[5];
    const float* W_hh   = (const float*)d_in[6];
    const float* b_ih   = (const float*)d_in[7];
    const float* b_hh   = (const float*)d_in[8];
    const float* h0     = (const float*)d_in[9];
    const float* c0     = (const float*)d_in[10];
    const int*   src    = (const int*)d_in[11];
    const int*   dst    = (const int*)d_in[12];
    float* out = (float*)d_out;

    char* base = (char*)d_ws;
    unsigned short* feat     = (unsigned short*)(base);               //  9,600,000 B
    unsigned short* xmid     = (unsigned short*)(base + 9600000);     //  9,600,000 B
    float*          el       = (float*)(base + 19200000);             //  200,000
    float*          er       = (float*)(base + 19400000);             //  200,000
    int*            cnt      = (int*)(base + 19600000);               //  200,000
    unsigned short* ebuf16   = (unsigned short*)(base + 19800000);    //  6,400,000 B
    unsigned short* Wb_frag  = (unsigned short*)(base + 26200000);    //  229,376
    float*          bsum     = (float*)(base + 26429376);             //  2,048
    unsigned short* Wfc_frag = (unsigned short*)(base + 26431424);    //  49,152
    // high-water ~26.5 MB

    hipMemsetAsync(cnt, 0, (size_t)N_NODES * sizeof(int), stream);

    k_prep<<<PREP_BLOCKS, 256, 0, stream>>>(W_fc, W_ih, W_hh, b_ih, b_hh,
                                            Wfc_frag, Wb_frag, bsum);

    k_featmm_bucket<<<FEAT_BLOCKS + BUCK_BLOCKS, 256, 0, stream>>>(
        x, Wfc_frag, attn_l, attn_r, feat, el, er, src, dst, cnt, ebuf16);

    k_gather<<<(N_NODES * 32 + 255) / 256, 256, 0, stream>>>(cnt, ebuf16, el, er,
                                                             feat, bias, xmid);

    k_lstm_persist<<<256, 256, 0, stream>>>(xmid, h0, Wb_frag, bsum, c0,
                                            out, out + N_NODES * OUT_DIM,
                                            out + 2 * N_NODES * OUT_DIM);
}

// Round 24
// 155.069 us; speedup vs baseline: 1.0945x; 1.0945x over previous
//
#include <hip/hip_runtime.h>
#include <math.h>

#define N_NODES 50000
#define E_EDGES 800000
#define IN_DIM  256
#define D_DIM   96
#define OUT_DIM 128
#define BKT     64         // fixed bucket stride (deg ~ Poisson(16); P(>=64) ~ 1e-18)
#define PREP_BLOCKS 448
#define FEAT_BLOCKS 782    // (50000+63)/64
#define BUCK_BLOCKS 3125   // ceil(E/256)
#define CAST_BLOCKS 3125   // ceil(N*128/8/256)
#define NTILES      3125   // 16-node tiles (3125*16 = 50000 exactly)

typedef __attribute__((ext_vector_type(8))) short short8;
typedef __attribute__((ext_vector_type(4))) float f32x4;

__device__ __forceinline__ unsigned short f2bf(float f) {
    unsigned u = __float_as_uint(f);
    unsigned r = u + 0x7fffu + ((u >> 16) & 1u);
    return (unsigned short)(r >> 16);
}
__device__ __forceinline__ float bf2f(unsigned short u) {
    return __uint_as_float(((unsigned)u) << 16);
}
__device__ __forceinline__ float sigm(float x) { return 1.f / (1.f + __expf(-x)); }
__device__ __forceinline__ float ftanh(float x) { return 1.f - 2.f / (1.f + __expf(2.f * x)); }

// slot swizzle: 16B slot s -> s ^ ((s>>4)&7). Same involution on write & read.
__device__ __forceinline__ int swz(int s) { return s ^ ((s >> 4) & 7); }

// pack 8 consecutive f32 -> short8 of bf16
__device__ __forceinline__ short8 pack8(const float* __restrict__ p) {
    float4 v0 = *(const float4*)p;
    float4 v1 = *(const float4*)(p + 4);
    union { short8 s; unsigned u[4]; } r;
    r.u[0] = (unsigned)f2bf(v0.x) | ((unsigned)f2bf(v0.y) << 16);
    r.u[1] = (unsigned)f2bf(v0.z) | ((unsigned)f2bf(v0.w) << 16);
    r.u[2] = (unsigned)f2bf(v1.x) | ((unsigned)f2bf(v1.y) << 16);
    r.u[3] = (unsigned)f2bf(v1.z) | ((unsigned)f2bf(v1.w) << 16);
    return r.s;
}

// ---------- K0: weight prep only ----------
__global__ __launch_bounds__(256)
void k_prep(const float* __restrict__ Wfc, const float* __restrict__ W_ih,
            const float* __restrict__ W_hh, const float* __restrict__ b_ih,
            const float* __restrict__ b_hh,
            unsigned short* __restrict__ Wfc_frag,
            unsigned short* __restrict__ Wb_frag, float* __restrict__ bsum) {
    int tid = blockIdx.x * 256 + threadIdx.x;
    if (tid < 512) bsum[tid] = b_ih[tid] + b_hh[tid];
    if (tid < 6 * 8 * 64 * 8) {          // Wfc_frag
        int j = tid & 7;
        int rest = tid >> 3;
        int l = rest & 63;
        int rest2 = rest >> 6;
        int ks = rest2 & 7;
        int cf = rest2 >> 3;
        int k   = ks * 32 + (l >> 4) * 8 + j;
        int col = cf * 16 + (l & 15);
        Wfc_frag[tid] = f2bf(Wfc[k * D_DIM + col]);
    }
    if (tid < 32 * 7 * 64 * 8) {         // Wb_frag
        int j = tid & 7;
        int rest = tid >> 3;
        int l = rest & 63;
        int rest2 = rest >> 6;
        int ks = rest2 % 7;
        int cf = rest2 / 7;
        int k   = ks * 32 + (l >> 4) * 8 + j;
        int col = cf * 16 + (l & 15);
        float v = (k < 96) ? W_ih[col * 96 + k] : W_hh[col * 128 + (k - 96)];
        Wb_frag[tid] = f2bf(v);
    }
}

// ---------- merged: featmm | edge bucket | h0 cast (R21 measured-best) ----------
__global__ __launch_bounds__(256, 2)
void k_featmm_bucket_cast(const float* __restrict__ x,
                          const unsigned short* __restrict__ Wfc_frag,
                          const float* __restrict__ al, const float* __restrict__ ar,
                          unsigned short* __restrict__ feat,
                          float* __restrict__ el, float* __restrict__ er,
                          const int* __restrict__ src, const int* __restrict__ dst,
                          int* __restrict__ cnt, unsigned short* __restrict__ ebuf16,
                          const float* __restrict__ h0, unsigned short* __restrict__ h0b) {
    if (blockIdx.x >= FEAT_BLOCKS) {
        int seg = blockIdx.x - FEAT_BLOCKS;
        if (seg < BUCK_BLOCKS) {
            int e = seg * 256 + threadIdx.x;
            if (e < E_EDGES) {
                int d = dst[e];
                int pos = atomicAdd(&cnt[d], 1);
                ebuf16[(size_t)d * BKT + pos] = (unsigned short)src[e];
            }
        } else {
            int tid = (seg - BUCK_BLOCKS) * 256 + threadIdx.x;
            if (tid < N_NODES * OUT_DIM / 8)
                *(short8*)(h0b + (size_t)tid * 8) = pack8(h0 + (size_t)tid * 8);
        }
        return;
    }
    const int t     = threadIdx.x;
    const int lane  = t & 63;
    const int w     = t >> 6;
    const int nfrag = lane & 15;
    const int khalf = lane >> 4;
    const int node  = blockIdx.x * 64 + w * 16 + nfrag;
    const int r     = min(node, N_NODES - 1);

    f32x4 acc[6];
#pragma unroll
    for (int cf = 0; cf < 6; ++cf) acc[cf] = (f32x4){0.f, 0.f, 0.f, 0.f};

    const float* px = x + (size_t)r * IN_DIM + khalf * 8;
    const unsigned short* pW = Wfc_frag + (size_t)lane * 8;

#pragma unroll 1
    for (int ks = 0; ks < 8; ++ks) {
        short8 xf = pack8(px + ks * 32);
#pragma unroll
        for (int cf = 0; cf < 6; ++cf) {
            short8 wf = *(const short8*)(pW + (size_t)((cf * 8 + ks) * 64) * 8);
            acc[cf] = __builtin_amdgcn_mfma_f32_16x16x32_bf16(wf, xf, acc[cf], 0, 0, 0);
        }
    }

    float sl = 0.f, sr = 0.f;
#pragma unroll
    for (int cf = 0; cf < 6; ++cf) {
        const int oc = cf * 16 + khalf * 4;
        const float4 a = *(const float4*)(al + oc);
        const float4 b = *(const float4*)(ar + oc);
        sl += acc[cf][0]*a.x + acc[cf][1]*a.y + acc[cf][2]*a.z + acc[cf][3]*a.w;
        sr += acc[cf][0]*b.x + acc[cf][1]*b.y + acc[cf][2]*b.z + acc[cf][3]*b.w;
    }
    sl += __shfl_xor(sl, 16, 64); sl += __shfl_xor(sl, 32, 64);
    sr += __shfl_xor(sr, 16, 64); sr += __shfl_xor(sr, 32, 64);

    if (node < N_NODES) {
        if (lane < 16) { el[node] = sl; er[node] = sr; }
#pragma unroll
        for (int cf = 0; cf < 6; ++cf) {
            const int oc = cf * 16 + khalf * 4;
            union { unsigned u[2]; } pk;
            pk.u[0] = (unsigned)f2bf(acc[cf][0]) | ((unsigned)f2bf(acc[cf][1]) << 16);
            pk.u[1] = (unsigned)f2bf(acc[cf][2]) | ((unsigned)f2bf(acc[cf][3]) << 16);
            *(uint2*)(feat + (size_t)node * D_DIM + oc) = make_uint2(pk.u[0], pk.u[1]);
        }
    }
}

// ---------- K3d: softmax-gather -> xmid bf16 [N,96] (R17 form) ----------
__global__ __launch_bounds__(256)
void k_gather(const int* __restrict__ cnt, const unsigned short* __restrict__ ebuf16,
              const float* __restrict__ el, const float* __restrict__ er,
              const unsigned short* __restrict__ feat, const float* __restrict__ bias,
              unsigned short* __restrict__ xmid) {
    const int n    = (blockIdx.x * 256 + threadIdx.x) >> 5;
    const int lane = threadIdx.x & 31;
    if (n >= N_NODES) return;
    const size_t o0 = (size_t)n * BKT;
    const int deg = cnt[n];
    const float ern = er[n];

    float a0 = 0.f, a1 = 0.f, a2 = 0.f;
    float inv;

    if (deg <= 32) {
        int   s_l = 0;
        float v_l = -INFINITY;
        if (lane < deg) {
            s_l = ebuf16[o0 + lane];
            float v = el[s_l] + ern; v_l = v > 0.f ? v : 0.2f * v;
        }
        float vmax = v_l;
#pragma unroll
        for (int d = 16; d; d >>= 1) vmax = fmaxf(vmax, __shfl_xor(vmax, d, 32));
        float w_l = (lane < deg) ? __expf(v_l - vmax) : 0.f;
        float ssum = w_l;
#pragma unroll
        for (int d = 16; d; d >>= 1) ssum += __shfl_xor(ssum, d, 32);
        inv = 1.f / (ssum > 0.f ? ssum : 1.f);

        for (int i = 0; i < deg; ++i) {
            int   s = __shfl(s_l, i, 32);
            float w = __shfl(w_l, i, 32);
            const unsigned short* fr = feat + (size_t)s * D_DIM;
            a0 += w * bf2f(fr[lane]);
            a1 += w * bf2f(fr[lane + 32]);
            a2 += w * bf2f(fr[lane + 64]);
        }
    } else {
        float vmax = -INFINITY;
        for (int i = lane; i < deg; i += 32) {
            int s = ebuf16[o0 + i];
            float v = el[s] + ern; v = v > 0.f ? v : 0.2f * v;
            vmax = fmaxf(vmax, v);
        }
#pragma unroll
        for (int d = 16; d; d >>= 1) vmax = fmaxf(vmax, __shfl_xor(vmax, d, 32));

        float ssum = 0.f;
        for (int i = lane; i < deg; i += 32) {
            int s = ebuf16[o0 + i];
            float v = el[s] + ern; v = v > 0.f ? v : 0.2f * v;
            ssum += __expf(v - vmax);
        }
#pragma unroll
        for (int d = 16; d; d >>= 1) ssum += __shfl_xor(ssum, d, 32);
        inv = 1.f / (ssum > 0.f ? ssum : 1.f);

        for (int bi0 = 0; bi0 < deg; bi0 += 32) {
            int   i_l = bi0 + lane;
            int   s_l = 0; float w_l = 0.f;
            if (i_l < deg) {
                s_l = ebuf16[o0 + i_l];
                float v = el[s_l] + ern; v = v > 0.f ? v : 0.2f * v;
                w_l = __expf(v - vmax);
            }
            int m = min(32, deg - bi0);
            for (int i = 0; i < m; ++i) {
                int   s = __shfl(s_l, i, 32);
                float w = __shfl(w_l, i, 32);
                const unsigned short* fr = feat + (size_t)s * D_DIM;
                a0 += w * bf2f(fr[lane]);
                a1 += w * bf2f(fr[lane + 32]);
                a2 += w * bf2f(fr[lane + 64]);
            }
        }
    }

    unsigned short* zr = xmid + (size_t)n * D_DIM;
    zr[lane]      = f2bf(ftanh(a0 * inv + bias[lane]));
    zr[lane + 32] = f2bf(ftanh(a1 * inv + bias[lane + 32]));
    zr[lane + 64] = f2bf(ftanh(a2 * inv + bias[lane + 64]));
}

// ---------- K4: persistent LSTM GEMM, weights in LDS, 8 waves / 2 tiles ----------
// 256 blocks x 512 threads (1/CU). Block covers col-half ch; wave-groups 0/1
// (4 waves each) process independent node tiles against the shared weight LDS.
// Uniform 13-iteration loop (tile = (b7*2+grp) + u*256, validity-guarded) so
// all 512 threads hit every barrier.
__global__ __launch_bounds__(512, 1)
void k_lstm_persist(const unsigned short* __restrict__ xmid,   // [N,96]  bf16
                    const unsigned short* __restrict__ h0b,    // [N,128] bf16
                    const unsigned short* __restrict__ Wb_frag,
                    const float* __restrict__ bsum,
                    const float* __restrict__ cin0,
                    float* __restrict__ out_h1a, float* __restrict__ out_h1b,
                    float* __restrict__ out_c1) {
    __shared__ unsigned short wlds[16 * 7 * 64 * 8];      // 114,688 B (shared by both groups)
    __shared__ unsigned short alds[2][2][7 * 64 * 8];     //  28,672 B ([grp][dbuf])
    const int t     = threadIdx.x;           // 0..511
    const int grp   = t >> 8;                // wave-group 0/1
    const int tl    = t & 255;               // tid within group
    const int lane  = tl & 63;
    const int wv    = tl >> 6;               // 0..3
    const int nfrag = lane & 15;
    const int khalf = lane >> 4;
    const int ch    = blockIdx.x >> 7;       // col-half 0/1
    const int b7    = blockIdx.x & 127;
    const int vlane = b7 * 2 + grp;          // virtual tile lane in [0,256)
    const int U     = (NTILES + 255) / 256;  // 13, uniform for all blocks

    // ---- load weight slice: 7168 x 16B chunks over 512 threads = 14 iters ----
#pragma unroll 2
    for (int it = 0; it < 14; ++it) {
        int cidx = t + it * 512;             // < 7168 always
        int wg   = cidx / 448;               // wv*4+g
        int rem  = cidx % 448;               // ks*64+l
        int cf   = ch * 4 + (wg >> 2) + 8 * (wg & 3);
        *(short8*)(wlds + (size_t)cidx * 8) =
            *(const short8*)(Wb_frag + ((size_t)cf * 448 + rem) * 8);
    }

    const int oc = ch * 64 + wv * 16 + khalf * 4;
    const float4 bi = *(const float4*)(bsum + oc);
    const float4 bf = *(const float4*)(bsum + 128 + oc);
    const float4 bg = *(const float4*)(bsum + 256 + oc);
    const float4 bo = *(const float4*)(bsum + 384 + oc);

    // per-thread static stage slots (depend only on tl)
    int s0, s1 = 0;
    {
        int q = tl;
        if (q < 192) { int rr = q / 12, ck = q % 12;
            s0 = (ck >> 2) * 64 + (ck & 3) * 16 + rr;
        } else { int p = q - 192; int rr = p >> 4, ck = p & 15;
            s0 = (3 + (ck >> 2)) * 64 + (ck & 3) * 16 + rr; }
        if (tl < 192) { int p = tl + 64;
            int rr = p >> 4, ck = p & 15;
            s1 = (3 + (ck >> 2)) * 64 + (ck & 3) * 16 + rr; }
    }

    // prefetch tile0 = vlane (< 256 < NTILES, always valid)
    short8 r0, r1;
    {
        int n0 = vlane * 16;
        if (tl < 192) { int rr = tl / 12, ck = tl % 12;
            r0 = *(const short8*)(xmid + (size_t)(n0 + rr) * D_DIM + ck * 8);
        } else { int p = tl - 192; int rr = p >> 4, ck = p & 15;
            r0 = *(const short8*)(h0b + (size_t)(n0 + rr) * OUT_DIM + ck * 8); }
        if (tl < 192) { int p = tl + 64; int rr = p >> 4, ck = p & 15;
            r1 = *(const short8*)(h0b + (size_t)(n0 + rr) * OUT_DIM + ck * 8); }
    }
    *(short8*)(alds[grp][0] + (size_t)swz(s0) * 8) = r0;
    if (tl < 192) *(short8*)(alds[grp][0] + (size_t)swz(s1) * 8) = r1;
    __syncthreads();

    for (int u = 0; u < U; ++u) {
        const int cur   = u & 1;
        const int tile  = vlane + u * 256;
        const bool valid  = tile < NTILES;
        const bool nvalid = (u + 1 < U) && (tile + 256 < NTILES);
        const int node  = tile * 16 + nfrag;

        // issue next tile's prefetch (hides under compute)
        if (nvalid) {
            int nn0 = (tile + 256) * 16;
            if (tl < 192) { int rr = tl / 12, ck = tl % 12;
                r0 = *(const short8*)(xmid + (size_t)(nn0 + rr) * D_DIM + ck * 8);
            } else { int p = tl - 192; int rr = p >> 4, ck = p & 15;
                r0 = *(const short8*)(h0b + (size_t)(nn0 + rr) * OUT_DIM + ck * 8); }
            if (tl < 192) { int p = tl + 64; int rr = p >> 4, ck = p & 15;
                r1 = *(const short8*)(h0b + (size_t)(nn0 + rr) * OUT_DIM + ck * 8); }
        }

        if (valid) {
            const float4 cv = *(const float4*)(cin0 + (size_t)node * OUT_DIM + oc);

            f32x4 acc[4];
#pragma unroll
            for (int g = 0; g < 4; ++g) acc[g] = (f32x4){0.f, 0.f, 0.f, 0.f};

#pragma unroll
            for (int ks = 0; ks < 7; ++ks) {
                short8 zf = *(const short8*)(alds[grp][cur] + (size_t)swz(ks * 64 + lane) * 8);
#pragma unroll
                for (int g = 0; g < 4; ++g) {
                    short8 wf = *(const short8*)(wlds +
                        (size_t)(((wv * 4 + g) * 7 + ks) * 64 + lane) * 8);
                    acc[g] = __builtin_amdgcn_mfma_f32_16x16x32_bf16(wf, zf, acc[g], 0, 0, 0);
                }
            }

            float4 h1, c1;
            c1.x = sigm(acc[1][0] + bf.x) * cv.x + sigm(acc[0][0] + bi.x) * ftanh(acc[2][0] + bg.x);
            c1.y = sigm(acc[1][1] + bf.y) * cv.y + sigm(acc[0][1] + bi.y) * ftanh(acc[2][1] + bg.y);
            c1.z = sigm(acc[1][2] + bf.z) * cv.z + sigm(acc[0][2] + bi.z) * ftanh(acc[2][2] + bg.z);
            c1.w = sigm(acc[1][3] + bf.w) * cv.w + sigm(acc[0][3] + bi.w) * ftanh(acc[2][3] + bg.w);
            h1.x = sigm(acc[3][0] + bo.x) * ftanh(c1.x);
            h1.y = sigm(acc[3][1] + bo.y) * ftanh(c1.y);
            h1.z = sigm(acc[3][2] + bo.z) * ftanh(c1.z);
            h1.w = sigm(acc[3][3] + bo.w) * ftanh(c1.w);
            *(float4*)(out_h1a + (size_t)node * OUT_DIM + oc) = h1;
            *(float4*)(out_h1b + (size_t)node * OUT_DIM + oc) = h1;
            *(float4*)(out_c1  + (size_t)node * OUT_DIM + oc) = c1;
        }

        if (nvalid) {
            *(short8*)(alds[grp][cur ^ 1] + (size_t)swz(s0) * 8) = r0;
            if (tl < 192) *(short8*)(alds[grp][cur ^ 1] + (size_t)swz(s1) * 8) = r1;
        }
        __syncthreads();
    }
}

extern "C" void kernel_launch(void* const* d_in, const int* in_sizes, int n_in,
                              void* d_out, int out_size, void* d_ws, size_t ws_size,
                              hipStream_t stream) {
    const float* x      = (const float*)d_in[0];
    const float* W_fc   = (const float*)d_in[1];
    const float* attn_l = (const float*)d_in[2];
    const float* attn_r = (const float*)d_in[3];
    const float* bias   = (const float*)d_in[4];
    const float* W_ih   = (const float*)d_in[5];
    const float* W_hh   = (const float*)d_in[6];
    const float* b_ih   = (const float*)d_in[7];
    const float* b_hh   = (const float*)d_in[8];
    const float* h0     = (const float*)d_in[9];
    const float* c0     = (const float*)d_in[10];
    const int*   src    = (const int*)d_in[11];
    const int*   dst    = (const int*)d_in[12];
    float* out = (float*)d_out;

    char* base = (char*)d_ws;
    unsigned short* feat     = (unsigned short*)(base);               //  9,600,000 B
    unsigned short* xmid     = (unsigned short*)(base + 9600000);     //  9,600,000 B
    unsigned short* h0b      = (unsigned short*)(base + 19200000);    // 12,800,000 B
    float*          el       = (float*)(base + 32000000);             //  200,000
    float*          er       = (float*)(base + 32200000);             //  200,000
    int*            cnt      = (int*)(base + 32400000);               //  200,000
    unsigned short* ebuf16   = (unsigned short*)(base + 32600000);    //  6,400,000 B
    unsigned short* Wb_frag  = (unsigned short*)(base + 39000000);    //  229,376
    float*          bsum     = (float*)(base + 39229376);             //  2,048
    unsigned short* Wfc_frag = (unsigned short*)(base + 39231424);    //  49,152
    // high-water ~39.3 MB

    hipMemsetAsync(cnt, 0, (size_t)N_NODES * sizeof(int), stream);

    k_prep<<<PREP_BLOCKS, 256, 0, stream>>>(W_fc, W_ih, W_hh, b_ih, b_hh,
                                            Wfc_frag, Wb_frag, bsum);

    k_featmm_bucket_cast<<<FEAT_BLOCKS + BUCK_BLOCKS + CAST_BLOCKS, 256, 0, stream>>>(
        x, Wfc_frag, attn_l, attn_r, feat, el, er, src, dst, cnt, ebuf16, h0, h0b);

    k_gather<<<(N_NODES * 32 + 255) / 256, 256, 0, stream>>>(cnt, ebuf16, el, er,
                                                             feat, bias, xmid);

    k_lstm_persist<<<256, 512, 0, stream>>>(xmid, h0b, Wb_frag, bsum, c0,
                                            out, out + N_NODES * OUT_DIM,
                                            out + 2 * N_NODES * OUT_DIM);
}

// Round 25
// 148.055 us; speedup vs baseline: 1.1464x; 1.0474x over previous
//
#include <hip/hip_runtime.h>
#include <math.h>

#define N_NODES 50000
#define E_EDGES 800000
#define IN_DIM  256
#define D_DIM   96
#define OUT_DIM 128
#define BKT     64         // fixed bucket stride (deg ~ Poisson(16); P(>=64) ~ 1e-18)
#define PREP_BLOCKS 196    // Wfc_frag (24576) + cnt zero (50000) via 50176 threads
#define FEAT_BLOCKS 782    // (50000+63)/64
#define BUCK_BLOCKS 3125   // ceil(E/256)
#define CAST_BLOCKS 3125   // ceil(N*128/8/256)
#define WPRP_BLOCKS 448    // Wb_frag 114688 entries
#define NTILES      3125   // 16-node tiles (3125*16 = 50000 exactly)

typedef __attribute__((ext_vector_type(8))) short short8;
typedef __attribute__((ext_vector_type(4))) float f32x4;

__device__ __forceinline__ unsigned short f2bf(float f) {
    unsigned u = __float_as_uint(f);
    unsigned r = u + 0x7fffu + ((u >> 16) & 1u);
    return (unsigned short)(r >> 16);
}
__device__ __forceinline__ float bf2f(unsigned short u) {
    return __uint_as_float(((unsigned)u) << 16);
}
__device__ __forceinline__ float sigm(float x) { return 1.f / (1.f + __expf(-x)); }
__device__ __forceinline__ float ftanh(float x) { return 1.f - 2.f / (1.f + __expf(2.f * x)); }

// slot swizzle: 16B slot s -> s ^ ((s>>4)&7). Same involution on write & read.
__device__ __forceinline__ int swz(int s) { return s ^ ((s >> 4) & 7); }

// pack 8 consecutive f32 -> short8 of bf16
__device__ __forceinline__ short8 pack8(const float* __restrict__ p) {
    float4 v0 = *(const float4*)p;
    float4 v1 = *(const float4*)(p + 4);
    union { short8 s; unsigned u[4]; } r;
    r.u[0] = (unsigned)f2bf(v0.x) | ((unsigned)f2bf(v0.y) << 16);
    r.u[1] = (unsigned)f2bf(v0.z) | ((unsigned)f2bf(v0.w) << 16);
    r.u[2] = (unsigned)f2bf(v1.x) | ((unsigned)f2bf(v1.y) << 16);
    r.u[3] = (unsigned)f2bf(v1.z) | ((unsigned)f2bf(v1.w) << 16);
    return r.s;
}

// ---------- K0: Wfc_frag prep + cnt zero (fbc's only true dependencies) ----------
__global__ __launch_bounds__(256)
void k_prep(const float* __restrict__ Wfc, unsigned short* __restrict__ Wfc_frag,
            int* __restrict__ cnt) {
    int tid = blockIdx.x * 256 + threadIdx.x;
    if (tid < 6 * 8 * 64 * 8) {          // Wfc_frag
        int j = tid & 7;
        int rest = tid >> 3;
        int l = rest & 63;
        int rest2 = rest >> 6;
        int ks = rest2 & 7;
        int cf = rest2 >> 3;
        int k   = ks * 32 + (l >> 4) * 8 + j;
        int col = cf * 16 + (l & 15);
        Wfc_frag[tid] = f2bf(Wfc[k * D_DIM + col]);
    }
    if (tid < N_NODES) cnt[tid] = 0;
}

// ---------- merged: featmm | edge bucket | h0 cast | Wb/bsum prep ----------
__global__ __launch_bounds__(256, 2)
void k_featmm_bucket_cast(const float* __restrict__ x,
                          const unsigned short* __restrict__ Wfc_frag,
                          const float* __restrict__ al, const float* __restrict__ ar,
                          unsigned short* __restrict__ feat,
                          float* __restrict__ el, float* __restrict__ er,
                          const int* __restrict__ src, const int* __restrict__ dst,
                          int* __restrict__ cnt, unsigned short* __restrict__ ebuf16,
                          const float* __restrict__ h0, unsigned short* __restrict__ h0b,
                          const float* __restrict__ W_ih, const float* __restrict__ W_hh,
                          const float* __restrict__ b_ih, const float* __restrict__ b_hh,
                          unsigned short* __restrict__ Wb_frag, float* __restrict__ bsum) {
    if (blockIdx.x >= FEAT_BLOCKS) {
        int seg = blockIdx.x - FEAT_BLOCKS;
        if (seg < BUCK_BLOCKS) {
            int e = seg * 256 + threadIdx.x;
            if (e < E_EDGES) {
                int d = dst[e];
                int pos = atomicAdd(&cnt[d], 1);
                ebuf16[(size_t)d * BKT + pos] = (unsigned short)src[e];
            }
        } else if (seg < BUCK_BLOCKS + CAST_BLOCKS) {
            int tid = (seg - BUCK_BLOCKS) * 256 + threadIdx.x;
            if (tid < N_NODES * OUT_DIM / 8)
                *(short8*)(h0b + (size_t)tid * 8) = pack8(h0 + (size_t)tid * 8);
        } else {
            // Wb_frag + bsum prep (consumed only by k_lstm_persist)
            int tid = (seg - BUCK_BLOCKS - CAST_BLOCKS) * 256 + threadIdx.x;
            if (tid < 512) bsum[tid] = b_ih[tid] + b_hh[tid];
            if (tid < 32 * 7 * 64 * 8) {
                int j = tid & 7;
                int rest = tid >> 3;
                int l = rest & 63;
                int rest2 = rest >> 6;
                int ks = rest2 % 7;
                int cf = rest2 / 7;
                int k   = ks * 32 + (l >> 4) * 8 + j;
                int col = cf * 16 + (l & 15);
                float v = (k < 96) ? W_ih[col * 96 + k] : W_hh[col * 128 + (k - 96)];
                Wb_frag[tid] = f2bf(v);
            }
        }
        return;
    }
    const int t     = threadIdx.x;
    const int lane  = t & 63;
    const int w     = t >> 6;
    const int nfrag = lane & 15;
    const int khalf = lane >> 4;
    const int node  = blockIdx.x * 64 + w * 16 + nfrag;
    const int r     = min(node, N_NODES - 1);

    f32x4 acc[6];
#pragma unroll
    for (int cf = 0; cf < 6; ++cf) acc[cf] = (f32x4){0.f, 0.f, 0.f, 0.f};

    const float* px = x + (size_t)r * IN_DIM + khalf * 8;
    const unsigned short* pW = Wfc_frag + (size_t)lane * 8;

#pragma unroll 1
    for (int ks = 0; ks < 8; ++ks) {
        short8 xf = pack8(px + ks * 32);
#pragma unroll
        for (int cf = 0; cf < 6; ++cf) {
            short8 wf = *(const short8*)(pW + (size_t)((cf * 8 + ks) * 64) * 8);
            acc[cf] = __builtin_amdgcn_mfma_f32_16x16x32_bf16(wf, xf, acc[cf], 0, 0, 0);
        }
    }

    float sl = 0.f, sr = 0.f;
#pragma unroll
    for (int cf = 0; cf < 6; ++cf) {
        const int oc = cf * 16 + khalf * 4;
        const float4 a = *(const float4*)(al + oc);
        const float4 b = *(const float4*)(ar + oc);
        sl += acc[cf][0]*a.x + acc[cf][1]*a.y + acc[cf][2]*a.z + acc[cf][3]*a.w;
        sr += acc[cf][0]*b.x + acc[cf][1]*b.y + acc[cf][2]*b.z + acc[cf][3]*b.w;
    }
    sl += __shfl_xor(sl, 16, 64); sl += __shfl_xor(sl, 32, 64);
    sr += __shfl_xor(sr, 16, 64); sr += __shfl_xor(sr, 32, 64);

    if (node < N_NODES) {
        if (lane < 16) { el[node] = sl; er[node] = sr; }
#pragma unroll
        for (int cf = 0; cf < 6; ++cf) {
            const int oc = cf * 16 + khalf * 4;
            union { unsigned u[2]; } pk;
            pk.u[0] = (unsigned)f2bf(acc[cf][0]) | ((unsigned)f2bf(acc[cf][1]) << 16);
            pk.u[1] = (unsigned)f2bf(acc[cf][2]) | ((unsigned)f2bf(acc[cf][3]) << 16);
            *(uint2*)(feat + (size_t)node * D_DIM + oc) = make_uint2(pk.u[0], pk.u[1]);
        }
    }
}

// ---------- K3d: softmax-gather -> xmid bf16 [N,96] (R17 form) ----------
__global__ __launch_bounds__(256)
void k_gather(const int* __restrict__ cnt, const unsigned short* __restrict__ ebuf16,
              const float* __restrict__ el, const float* __restrict__ er,
              const unsigned short* __restrict__ feat, const float* __restrict__ bias,
              unsigned short* __restrict__ xmid) {
    const int n    = (blockIdx.x * 256 + threadIdx.x) >> 5;
    const int lane = threadIdx.x & 31;
    if (n >= N_NODES) return;
    const size_t o0 = (size_t)n * BKT;
    const int deg = cnt[n];
    const float ern = er[n];

    float a0 = 0.f, a1 = 0.f, a2 = 0.f;
    float inv;

    if (deg <= 32) {
        int   s_l = 0;
        float v_l = -INFINITY;
        if (lane < deg) {
            s_l = ebuf16[o0 + lane];
            float v = el[s_l] + ern; v_l = v > 0.f ? v : 0.2f * v;
        }
        float vmax = v_l;
#pragma unroll
        for (int d = 16; d; d >>= 1) vmax = fmaxf(vmax, __shfl_xor(vmax, d, 32));
        float w_l = (lane < deg) ? __expf(v_l - vmax) : 0.f;
        float ssum = w_l;
#pragma unroll
        for (int d = 16; d; d >>= 1) ssum += __shfl_xor(ssum, d, 32);
        inv = 1.f / (ssum > 0.f ? ssum : 1.f);

        for (int i = 0; i < deg; ++i) {
            int   s = __shfl(s_l, i, 32);
            float w = __shfl(w_l, i, 32);
            const unsigned short* fr = feat + (size_t)s * D_DIM;
            a0 += w * bf2f(fr[lane]);
            a1 += w * bf2f(fr[lane + 32]);
            a2 += w * bf2f(fr[lane + 64]);
        }
    } else {
        float vmax = -INFINITY;
        for (int i = lane; i < deg; i += 32) {
            int s = ebuf16[o0 + i];
            float v = el[s] + ern; v = v > 0.f ? v : 0.2f * v;
            vmax = fmaxf(vmax, v);
        }
#pragma unroll
        for (int d = 16; d; d >>= 1) vmax = fmaxf(vmax, __shfl_xor(vmax, d, 32));

        float ssum = 0.f;
        for (int i = lane; i < deg; i += 32) {
            int s = ebuf16[o0 + i];
            float v = el[s] + ern; v = v > 0.f ? v : 0.2f * v;
            ssum += __expf(v - vmax);
        }
#pragma unroll
        for (int d = 16; d; d >>= 1) ssum += __shfl_xor(ssum, d, 32);
        inv = 1.f / (ssum > 0.f ? ssum : 1.f);

        for (int bi0 = 0; bi0 < deg; bi0 += 32) {
            int   i_l = bi0 + lane;
            int   s_l = 0; float w_l = 0.f;
            if (i_l < deg) {
                s_l = ebuf16[o0 + i_l];
                float v = el[s_l] + ern; v = v > 0.f ? v : 0.2f * v;
                w_l = __expf(v - vmax);
            }
            int m = min(32, deg - bi0);
            for (int i = 0; i < m; ++i) {
                int   s = __shfl(s_l, i, 32);
                float w = __shfl(w_l, i, 32);
                const unsigned short* fr = feat + (size_t)s * D_DIM;
                a0 += w * bf2f(fr[lane]);
                a1 += w * bf2f(fr[lane + 32]);
                a2 += w * bf2f(fr[lane + 64]);
            }
        }
    }

    unsigned short* zr = xmid + (size_t)n * D_DIM;
    zr[lane]      = f2bf(ftanh(a0 * inv + bias[lane]));
    zr[lane + 32] = f2bf(ftanh(a1 * inv + bias[lane + 32]));
    zr[lane + 64] = f2bf(ftanh(a2 * inv + bias[lane + 64]));
}

// ---------- K4: persistent LSTM GEMM, weights in LDS, 8 waves / 2 tiles ----------
__global__ __launch_bounds__(512, 1)
void k_lstm_persist(const unsigned short* __restrict__ xmid,   // [N,96]  bf16
                    const unsigned short* __restrict__ h0b,    // [N,128] bf16
                    const unsigned short* __restrict__ Wb_frag,
                    const float* __restrict__ bsum,
                    const float* __restrict__ cin0,
                    float* __restrict__ out_h1a, float* __restrict__ out_h1b,
                    float* __restrict__ out_c1) {
    __shared__ unsigned short wlds[16 * 7 * 64 * 8];      // 114,688 B (shared by both groups)
    __shared__ unsigned short alds[2][2][7 * 64 * 8];     //  28,672 B ([grp][dbuf])
    const int t     = threadIdx.x;           // 0..511
    const int grp   = t >> 8;                // wave-group 0/1
    const int tl    = t & 255;               // tid within group
    const int lane  = tl & 63;
    const int wv    = tl >> 6;               // 0..3
    const int nfrag = lane & 15;
    const int khalf = lane >> 4;
    const int ch    = blockIdx.x >> 7;       // col-half 0/1
    const int b7    = blockIdx.x & 127;
    const int vlane = b7 * 2 + grp;          // virtual tile lane in [0,256)
    const int U     = (NTILES + 255) / 256;  // 13, uniform for all blocks

    // ---- load weight slice: 7168 x 16B chunks over 512 threads = 14 iters ----
#pragma unroll 2
    for (int it = 0; it < 14; ++it) {
        int cidx = t + it * 512;             // < 7168 always
        int wg   = cidx / 448;               // wv*4+g
        int rem  = cidx % 448;               // ks*64+l
        int cf   = ch * 4 + (wg >> 2) + 8 * (wg & 3);
        *(short8*)(wlds + (size_t)cidx * 8) =
            *(const short8*)(Wb_frag + ((size_t)cf * 448 + rem) * 8);
    }

    const int oc = ch * 64 + wv * 16 + khalf * 4;
    const float4 bi = *(const float4*)(bsum + oc);
    const float4 bf = *(const float4*)(bsum + 128 + oc);
    const float4 bg = *(const float4*)(bsum + 256 + oc);
    const float4 bo = *(const float4*)(bsum + 384 + oc);

    // per-thread static stage slots (depend only on tl)
    int s0, s1 = 0;
    {
        int q = tl;
        if (q < 192) { int rr = q / 12, ck = q % 12;
            s0 = (ck >> 2) * 64 + (ck & 3) * 16 + rr;
        } else { int p = q - 192; int rr = p >> 4, ck = p & 15;
            s0 = (3 + (ck >> 2)) * 64 + (ck & 3) * 16 + rr; }
        if (tl < 192) { int p = tl + 64;
            int rr = p >> 4, ck = p & 15;
            s1 = (3 + (ck >> 2)) * 64 + (ck & 3) * 16 + rr; }
    }

    // prefetch tile0 = vlane (< 256 < NTILES, always valid)
    short8 r0, r1;
    {
        int n0 = vlane * 16;
        if (tl < 192) { int rr = tl / 12, ck = tl % 12;
            r0 = *(const short8*)(xmid + (size_t)(n0 + rr) * D_DIM + ck * 8);
        } else { int p = tl - 192; int rr = p >> 4, ck = p & 15;
            r0 = *(const short8*)(h0b + (size_t)(n0 + rr) * OUT_DIM + ck * 8); }
        if (tl < 192) { int p = tl + 64; int rr = p >> 4, ck = p & 15;
            r1 = *(const short8*)(h0b + (size_t)(n0 + rr) * OUT_DIM + ck * 8); }
    }
    *(short8*)(alds[grp][0] + (size_t)swz(s0) * 8) = r0;
    if (tl < 192) *(short8*)(alds[grp][0] + (size_t)swz(s1) * 8) = r1;
    __syncthreads();

    for (int u = 0; u < U; ++u) {
        const int cur   = u & 1;
        const int tile  = vlane + u * 256;
        const bool valid  = tile < NTILES;
        const bool nvalid = (u + 1 < U) && (tile + 256 < NTILES);
        const int node  = tile * 16 + nfrag;

        // issue next tile's prefetch (hides under compute)
        if (nvalid) {
            int nn0 = (tile + 256) * 16;
            if (tl < 192) { int rr = tl / 12, ck = tl % 12;
                r0 = *(const short8*)(xmid + (size_t)(nn0 + rr) * D_DIM + ck * 8);
            } else { int p = tl - 192; int rr = p >> 4, ck = p & 15;
                r0 = *(const short8*)(h0b + (size_t)(nn0 + rr) * OUT_DIM + ck * 8); }
            if (tl < 192) { int p = tl + 64; int rr = p >> 4, ck = p & 15;
                r1 = *(const short8*)(h0b + (size_t)(nn0 + rr) * OUT_DIM + ck * 8); }
        }

        if (valid) {
            const float4 cv = *(const float4*)(cin0 + (size_t)node * OUT_DIM + oc);

            f32x4 acc[4];
#pragma unroll
            for (int g = 0; g < 4; ++g) acc[g] = (f32x4){0.f, 0.f, 0.f, 0.f};

#pragma unroll
            for (int ks = 0; ks < 7; ++ks) {
                short8 zf = *(const short8*)(alds[grp][cur] + (size_t)swz(ks * 64 + lane) * 8);
#pragma unroll
                for (int g = 0; g < 4; ++g) {
                    short8 wf = *(const short8*)(wlds +
                        (size_t)(((wv * 4 + g) * 7 + ks) * 64 + lane) * 8);
                    acc[g] = __builtin_amdgcn_mfma_f32_16x16x32_bf16(wf, zf, acc[g], 0, 0, 0);
                }
            }

            float4 h1, c1;
            c1.x = sigm(acc[1][0] + bf.x) * cv.x + sigm(acc[0][0] + bi.x) * ftanh(acc[2][0] + bg.x);
            c1.y = sigm(acc[1][1] + bf.y) * cv.y + sigm(acc[0][1] + bi.y) * ftanh(acc[2][1] + bg.y);
            c1.z = sigm(acc[1][2] + bf.z) * cv.z + sigm(acc[0][2] + bi.z) * ftanh(acc[2][2] + bg.z);
            c1.w = sigm(acc[1][3] + bf.w) * cv.w + sigm(acc[0][3] + bi.w) * ftanh(acc[2][3] + bg.w);
            h1.x = sigm(acc[3][0] + bo.x) * ftanh(c1.x);
            h1.y = sigm(acc[3][1] + bo.y) * ftanh(c1.y);
            h1.z = sigm(acc[3][2] + bo.z) * ftanh(c1.z);
            h1.w = sigm(acc[3][3] + bo.w) * ftanh(c1.w);
            *(float4*)(out_h1a + (size_t)node * OUT_DIM + oc) = h1;
            *(float4*)(out_h1b + (size_t)node * OUT_DIM + oc) = h1;
            *(float4*)(out_c1  + (size_t)node * OUT_DIM + oc) = c1;
        }

        if (nvalid) {
            *(short8*)(alds[grp][cur ^ 1] + (size_t)swz(s0) * 8) = r0;
            if (tl < 192) *(short8*)(alds[grp][cur ^ 1] + (size_t)swz(s1) * 8) = r1;
        }
        __syncthreads();
    }
}

extern "C" void kernel_launch(void* const* d_in, const int* in_sizes, int n_in,
                              void* d_out, int out_size, void* d_ws, size_t ws_size,
                              hipStream_t stream) {
    const float* x      = (const float*)d_in[0];
    const float* W_fc   = (const float*)d_in[1];
    const float* attn_l = (const float*)d_in[2];
    const float* attn_r = (const float*)d_in[3];
    const float* bias   = (const float*)d_in[4];
    const float* W_ih   = (const float*)d_in[5];
    const float* W_hh   = (const float*)d_in[6];
    const float* b_ih   = (const float*)d_in[7];
    const float* b_hh   = (const float*)d_in[8];
    const float* h0     = (const float*)d_in[9];
    const float* c0     = (const float*)d_in[10];
    const int*   src    = (const int*)d_in[11];
    const int*   dst    = (const int*)d_in[12];
    float* out = (float*)d_out;

    char* base = (char*)d_ws;
    unsigned short* feat     = (unsigned short*)(base);               //  9,600,000 B
    unsigned short* xmid     = (unsigned short*)(base + 9600000);     //  9,600,000 B
    unsigned short* h0b      = (unsigned short*)(base + 19200000);    // 12,800,000 B
    float*          el       = (float*)(base + 32000000);             //  200,000
    float*          er       = (float*)(base + 32200000);             //  200,000
    int*            cnt      = (int*)(base + 32400000);               //  200,000
    unsigned short* ebuf16   = (unsigned short*)(base + 32600000);    //  6,400,000 B
    unsigned short* Wb_frag  = (unsigned short*)(base + 39000000);    //  229,376
    float*          bsum     = (float*)(base + 39229376);             //  2,048
    unsigned short* Wfc_frag = (unsigned short*)(base + 39231424);    //  49,152
    // high-water ~39.3 MB

    k_prep<<<PREP_BLOCKS, 256, 0, stream>>>(W_fc, Wfc_frag, cnt);

    k_featmm_bucket_cast<<<FEAT_BLOCKS + BUCK_BLOCKS + CAST_BLOCKS + WPRP_BLOCKS,
                           256, 0, stream>>>(
        x, Wfc_frag, attn_l, attn_r, feat, el, er, src, dst, cnt, ebuf16, h0, h0b,
        W_ih, W_hh, b_ih, b_hh, Wb_frag, bsum);

    k_gather<<<(N_NODES * 32 + 255) / 256, 256, 0, stream>>>(cnt, ebuf16, el, er,
                                                             feat, bias, xmid);

    k_lstm_persist<<<256, 512, 0, stream>>>(xmid, h0b, Wb_frag, bsum, c0,
                                            out, out + N_NODES * OUT_DIM,
                                            out + 2 * N_NODES * OUT_DIM);
}